// Round 10
// baseline (233.154 us; speedup 1.0000x reference)
//
#include <hip/hip_runtime.h>
#include <hip/hip_bf16.h>
#include <stdint.h>

#define DIM   1024
#define HEADS 16
#define HD    64
#define NB    8
#define NTOK  1024
#define MROWS (NB*NTOK)   // 8192 rows for x and for context

#define LOG2E 1.4426950408889634f
#define SCL   (0.125f * LOG2E)

typedef __attribute__((ext_vector_type(8))) _Float16 f16x8;
typedef __attribute__((ext_vector_type(4))) _Float16 f16x4;
typedef __attribute__((ext_vector_type(4))) float    f32x4;

typedef unsigned int uint_as1 __attribute__((address_space(1)));
typedef unsigned int uint_as3 __attribute__((address_space(3)));

__device__ __forceinline__ void gload16(const void* g, void* l) {
    __builtin_amdgcn_global_load_lds((const uint_as1*)g, (uint_as3*)l, 16, 0, 0);
}

__device__ __forceinline__ unsigned pkrtz(float a, float b) {
    auto h = __builtin_amdgcn_cvt_pkrtz(a, b);   // __fp16 ext_vector(2)
    return __builtin_bit_cast(unsigned, h);
}

// ---- permlane pair swaps (gfx950), with verified shuffle fallback ----
#if __has_builtin(__builtin_amdgcn_permlane32_swap)
__device__ __forceinline__ void swap32(unsigned& a, unsigned& b) {
    auto r = __builtin_amdgcn_permlane32_swap(a, b, false, false);
    a = r[0]; b = r[1];
}
#else
__device__ __forceinline__ void swap32(unsigned& a, unsigned& b) {
    unsigned as = (unsigned)__shfl_xor((int)a, 32, 64);
    unsigned bs = (unsigned)__shfl_xor((int)b, 32, 64);
    bool lo = ((threadIdx.x & 63) < 32);
    unsigned na = lo ? a : bs, nb = lo ? as : b;
    a = na; b = nb;
}
#endif
#if __has_builtin(__builtin_amdgcn_permlane16_swap)
__device__ __forceinline__ void swap16(unsigned& a, unsigned& b) {
    auto r = __builtin_amdgcn_permlane16_swap(a, b, false, false);
    a = r[0]; b = r[1];
}
#else
__device__ __forceinline__ void swap16(unsigned& a, unsigned& b) {
    unsigned as = (unsigned)__shfl_xor((int)a, 16, 64);
    unsigned bs = (unsigned)__shfl_xor((int)b, 16, 64);
    bool ev = ((threadIdx.x & 16) == 0);
    unsigned na = ev ? a : bs, nb = ev ? as : b;
    a = na; b = nb;
}
#endif
__device__ __forceinline__ float redsum32(float x) {
    unsigned a = __builtin_bit_cast(unsigned, x), b = a;
    swap32(a, b);
    return __builtin_bit_cast(float, a) + __builtin_bit_cast(float, b);
}
__device__ __forceinline__ float redsum16(float x) {
    unsigned a = __builtin_bit_cast(unsigned, x), b = a;
    swap16(a, b);
    return __builtin_bit_cast(float, a) + __builtin_bit_cast(float, b);
}

// ---------------- LayerNorm: fp32 in -> fp16 out ----------------
__global__ __launch_bounds__(256) void ln_kernel(const float* __restrict__ x,
                                                 const float* __restrict__ ctx,
                                                 const float* __restrict__ gamma,
                                                 const float* __restrict__ beta,
                                                 _Float16* __restrict__ xn,
                                                 _Float16* __restrict__ cn) {
    int row = blockIdx.x;
    const float* src; _Float16* dst;
    if (row < MROWS) { src = x + (size_t)row * DIM;          dst = xn + (size_t)row * DIM; }
    else             { int r = row - MROWS;
                       src = ctx + (size_t)r * DIM;          dst = cn + (size_t)r * DIM; }
    int t = threadIdx.x;
    float4 v = *(const float4*)(src + t * 4);
    float s  = v.x + v.y + v.z + v.w;
    float s2 = v.x*v.x + v.y*v.y + v.z*v.z + v.w*v.w;
    #pragma unroll
    for (int o = 32; o; o >>= 1) { s += __shfl_xor(s, o, 64); s2 += __shfl_xor(s2, o, 64); }
    __shared__ float red[8];
    int w = t >> 6, l = t & 63;
    if (l == 0) { red[w] = s; red[4 + w] = s2; }
    __syncthreads();
    s  = red[0] + red[1] + red[2] + red[3];
    s2 = red[4] + red[5] + red[6] + red[7];
    float mu   = s * (1.0f / DIM);
    float rstd = rsqrtf(s2 * (1.0f / DIM) - mu * mu + 1e-5f);
    float4 g  = *(const float4*)(gamma + t * 4);
    float4 bb = *(const float4*)(beta  + t * 4);
    f16x4 o;
    o[0] = (_Float16)((v.x - mu) * rstd * g.x + bb.x);
    o[1] = (_Float16)((v.y - mu) * rstd * g.y + bb.y);
    o[2] = (_Float16)((v.z - mu) * rstd * g.z + bb.z);
    o[3] = (_Float16)((v.w - mu) * rstd * g.w + bb.w);
    *(f16x4*)(dst + t * 4) = o;
}

// ---------------- Bias convert: f32 -> f16 * log2e -------------------------
__global__ __launch_bounds__(256) void biasconv_kernel(const float* __restrict__ bias,
                                                       _Float16* __restrict__ bias2) {
    size_t i = ((size_t)blockIdx.x * 256 + threadIdx.x) * 8;
    float4 a = *(const float4*)(bias + i);
    float4 b = *(const float4*)(bias + i + 4);
    f16x8 o;
    o[0] = (_Float16)(a.x * LOG2E); o[1] = (_Float16)(a.y * LOG2E);
    o[2] = (_Float16)(a.z * LOG2E); o[3] = (_Float16)(a.w * LOG2E);
    o[4] = (_Float16)(b.x * LOG2E); o[5] = (_Float16)(b.y * LOG2E);
    o[6] = (_Float16)(b.z * LOG2E); o[7] = (_Float16)(b.w * LOG2E);
    *(f16x8*)(bias2 + i) = o;
}

// ---------------- Weight transpose + cast: W[k][j] fp32 -> WT[j][k] fp16 ----
__global__ __launch_bounds__(256) void wtrans_kernel(const float* __restrict__ Wq, const float* __restrict__ Wk,
                                                     const float* __restrict__ Wv, const float* __restrict__ Wo,
                                                     _Float16* __restrict__ Tq, _Float16* __restrict__ Tk,
                                                     _Float16* __restrict__ Tv, _Float16* __restrict__ To) {
    __shared__ float tile[32][33];
    int m = blockIdx.z;
    const float* W = (m == 0) ? Wq : (m == 1) ? Wk : (m == 2) ? Wv : Wo;
    _Float16*    T = (m == 0) ? Tq : (m == 1) ? Tk : (m == 2) ? Tv : To;
    int j0 = blockIdx.x * 32, k0 = blockIdx.y * 32;
    int tx = threadIdx.x, ty = threadIdx.y;   // 32 x 8
    #pragma unroll
    for (int i = 0; i < 4; i++) tile[ty + i*8][tx] = W[(size_t)(k0 + ty + i*8) * DIM + j0 + tx];
    __syncthreads();
    #pragma unroll
    for (int i = 0; i < 4; i++) T[(size_t)(j0 + ty + i*8) * DIM + k0 + tx] = (_Float16)tile[tx][ty + i*8];
}

// ---------------- GEMM: C = A @ BT^T, BK=64, XOR-swizzled LDS --------------
// MODE 0: C -> [b][h][n][d] f16 (K layout)    MODE 1: same + SCL scale (Q)
// MODE 2: C -> [b][h][d][n] f16 (V^T layout)  MODE 3: C -> fp32 + bias
// MODE 4: N=2048 fused K+V: gn<1024 -> K layout to Cout; else V^T to Cout2
template<int MODE>
__global__ __launch_bounds__(256) void gemm_bt(const _Float16* __restrict__ A,
                                               const _Float16* __restrict__ BT,
                                               void* __restrict__ Cout,
                                               void* __restrict__ Cout2,
                                               const float* __restrict__ bias) {
    __shared__ _Float16 As[128 * 64];
    __shared__ _Float16 Bs[128 * 64];
    const int K = DIM;
    int m0 = blockIdx.x * 128, n0 = blockIdx.y * 128;
    int t = threadIdx.x, w = t >> 6, l = t & 63;
    int wr = w >> 1, wc = w & 1, ln = l & 15, qtr = l >> 4;
    f32x4 acc[4][4] = {};
    int srow = w * 8 + (l >> 3);
    int cg   = (l & 7) ^ (srow & 7);
    const _Float16* Ag = A  + (size_t)(m0 + srow) * K + cg * 8;
    const _Float16* Bg = BT + (size_t)(n0 + srow) * K + cg * 8;
    for (int kt = 0; kt < K; kt += 64) {
        #pragma unroll
        for (int p = 0; p < 4; p++) {
            gload16(Ag + (size_t)(p * 32) * K, &As[(p * 32 + w * 8) * 64]);
            gload16(Bg + (size_t)(p * 32) * K, &Bs[(p * 32 + w * 8) * 64]);
        }
        Ag += 64; Bg += 64;
        __syncthreads();
        #pragma unroll
        for (int kk = 0; kk < 2; kk++) {
            f16x8 af[4], bfr[4];
            #pragma unroll
            for (int r = 0; r < 4; r++)
                af[r]  = *(const f16x8*)&As[(wr * 64 + r * 16 + ln) * 64 + (((qtr + kk*4) ^ (ln & 7)) * 8)];
            #pragma unroll
            for (int c = 0; c < 4; c++)
                bfr[c] = *(const f16x8*)&Bs[(wc * 64 + c * 16 + ln) * 64 + (((qtr + kk*4) ^ (ln & 7)) * 8)];
            #pragma unroll
            for (int r = 0; r < 4; r++)
                #pragma unroll
                for (int c = 0; c < 4; c++)
                    acc[r][c] = __builtin_amdgcn_mfma_f32_16x16x32_f16(af[r], bfr[c], acc[r][c], 0, 0, 0);
        }
        __syncthreads();
    }
    #pragma unroll
    for (int r = 0; r < 4; r++)
        #pragma unroll
        for (int c = 0; c < 4; c++) {
            int gn = n0 + wc * 64 + c * 16 + ln;
            #pragma unroll
            for (int q = 0; q < 4; q++) {
                int gm = m0 + wr * 64 + r * 16 + qtr * 4 + q;
                float v = acc[r][c][q];
                if constexpr (MODE == 0 || MODE == 1) {
                    int b = gm >> 10, n = gm & 1023, h = gn >> 6, d = gn & 63;
                    float sc = (MODE == 1) ? SCL : 1.0f;
                    ((_Float16*)Cout)[(((size_t)(b * HEADS + h) * NTOK + n) << 6) + d] = (_Float16)(v * sc);
                } else if constexpr (MODE == 2) {
                    int b = gm >> 10, n = gm & 1023, h = gn >> 6, d = gn & 63;
                    ((_Float16*)Cout)[(((size_t)(b * HEADS + h) * HD + d) << 10) + n] = (_Float16)v;
                } else if constexpr (MODE == 4) {
                    int b = gm >> 10, n = gm & 1023;
                    if (gn < 1024) {
                        int h = gn >> 6, d = gn & 63;
                        ((_Float16*)Cout)[(((size_t)(b * HEADS + h) * NTOK + n) << 6) + d] = (_Float16)v;
                    } else {
                        int g2 = gn - 1024, h = g2 >> 6, d = g2 & 63;
                        ((_Float16*)Cout2)[(((size_t)(b * HEADS + h) * HD + d) << 10) + n] = (_Float16)v;
                    }
                } else {
                    ((float*)Cout)[(size_t)gm * DIM + gn] = v + bias[gn];
                }
            }
        }
}

// ---------------- Fused flash attention -----------------------------------
// Block = (b, h, 64 q rows); 4 waves x 16 q rows each. 2048 blocks.
// XCD swizzle groups blocks by h-PAIR (bias2 slices L2-resident per XCD).
// Swapped QK^T with bias as MFMA C-init (Q pre-scaled by 0.125*log2e in GEMM).
// No online max (log2-domain scores bounded); l reduced once in epilogue.
// Permlane P^T->A-frag exchange.
__global__ __launch_bounds__(256) void attn_kernel(const _Float16* __restrict__ qb,
                                                   const _Float16* __restrict__ kb,
                                                   const _Float16* __restrict__ vt,
                                                   const _Float16* __restrict__ bias2,
                                                   _Float16* __restrict__ ao) {
    __shared__ _Float16 Kt[2][64 * 64];
    __shared__ _Float16 Vs[2][64 * 64];
    int bid = blockIdx.x;
    // XCD = bid&7 = h-pair; rem packs (h&1, b, qt)
    int rem = bid >> 3;
    int h = (bid & 7) * 2 + (rem & 1);
    int b = (rem >> 1) & 7;
    int qt = rem >> 4;            // 0..15
    int q0 = qt * 64;
    int t = threadIdx.x, w = t >> 6, l = t & 63, ln = l & 15, qtr = l >> 4;
    const _Float16* qbase = qb + (size_t)(b * HEADS + h) * NTOK * HD;
    const _Float16* kbase = kb + (size_t)(b * HEADS + h) * NTOK * HD;
    const _Float16* vbase = vt + (size_t)(b * HEADS + h) * HD * NTOK;
    const _Float16* bbase = bias2 + ((size_t)h * NTOK + q0 + w * 16) * NTOK;

    // Q fragments (B-operand): lane ln = q col, qtr*8 = k offset
    f16x8 qfr[2];
    #pragma unroll
    for (int ks = 0; ks < 2; ks++)
        qfr[ks] = *(const f16x8*)&qbase[(size_t)(q0 + w*16 + ln) * HD + ks*32 + qtr*8];

#define STAGE(BUF, J0) do {                                                     \
        int rb_ = w * 16;                                                       \
        _Float16* kl_ = &Kt[BUF][rb_ * 64];                                     \
        _Float16* vl_ = &Vs[BUF][rb_ * 64];                                     \
        int r_ = rb_ + (l >> 3); int cg_ = (l & 7) ^ (r_ & 7);                  \
        gload16(kbase + (size_t)((J0) + r_) * HD + cg_ * 8, kl_);               \
        gload16(vbase + (size_t)r_ * NTOK + (J0) + cg_ * 8, vl_);               \
        r_ += 8; cg_ = (l & 7) ^ (r_ & 7);                                      \
        gload16(kbase + (size_t)((J0) + r_) * HD + cg_ * 8, kl_ + 8 * 64);      \
        gload16(vbase + (size_t)r_ * NTOK + (J0) + cg_ * 8, vl_ + 8 * 64);      \
    } while (0)

#define LOADB(DST, TT) do {                                                     \
        _Pragma("unroll")                                                       \
        for (int r_ = 0; r_ < 4; r_++)                                          \
            DST[r_] = *(const f16x4*)&bbase[(size_t)ln * NTOK                   \
                                            + (TT)*64 + qtr*4 + r_*16];         \
    } while (0)

    STAGE(0, 0);
    f16x4 bpp[2][4];              // [ping][r], static-indexed after unroll
    LOADB(bpp[0], 0);
    __syncthreads();

    float l_part = 0.f;
    f32x4 acc[4] = {};

    #pragma unroll 2
    for (int tt = 0; tt < 16; tt++) {
        int cur = tt & 1;
        if (tt < 15) { STAGE(cur ^ 1, (tt + 1) * 64); LOADB(bpp[cur ^ 1], tt + 1); }

        // ---- QK^T (swapped) with bias C-init:
        // st2[r][m] = bias_log2 + S_log2 at [j=tt*64+r*16+qtr*4+m][q=q0+w*16+ln]
        f32x4 st2[4];
        #pragma unroll
        for (int r = 0; r < 4; r++) {
            f16x4 bb = bpp[cur][r];
            f32x4 ci = {(float)bb[0], (float)bb[1], (float)bb[2], (float)bb[3]};
            st2[r] = ci;
        }
        __builtin_amdgcn_s_setprio(1);
        #pragma unroll
        for (int r = 0; r < 4; r++) {
            int row = r * 16 + ln;
            #pragma unroll
            for (int ks = 0; ks < 2; ks++) {
                f16x8 kf = *(const f16x8*)&Kt[cur][row * 64 + (((qtr + ks*4) ^ (ln & 7)) * 8)];
                st2[r] = __builtin_amdgcn_mfma_f32_16x16x32_f16(kf, qfr[ks], st2[r], 0, 0, 0);
            }
        }
        __builtin_amdgcn_s_setprio(0);

        // ---- softmax numerator (no max: P = exp2(s) directly, f16-safe)
        float sig = 0.f;
        unsigned pk2[4][2];
        #pragma unroll
        for (int r = 0; r < 4; r++) {
            float p0 = exp2f(st2[r][0]);
            float p1 = exp2f(st2[r][1]);
            float p2 = exp2f(st2[r][2]);
            float p3 = exp2f(st2[r][3]);
            sig += (p0 + p1) + (p2 + p3);
            pk2[r][0] = pkrtz(p0, p1);
            pk2[r][1] = pkrtz(p2, p3);
        }
        l_part += sig;

        // in-register P^T -> A-frag exchange via permlane swaps
        f16x8 pfr[2];
        #pragma unroll
        for (int ks = 0; ks < 2; ks++) {
            unsigned pw[4];
            #pragma unroll
            for (int c = 0; c < 2; c++) {
                unsigned U = pk2[2*ks][c], T = pk2[2*ks + 1][c];
                swap32(U, T);
                swap16(U, T);
                pw[c]     = U;    // elems e=0..3
                pw[2 + c] = T;    // elems e=4..7
            }
            pfr[ks] = __builtin_bit_cast(f16x8, *(const uint4*)pw);
        }

        // ---- PV: acc[dg] += P @ V
        __builtin_amdgcn_s_setprio(1);
        #pragma unroll
        for (int dg = 0; dg < 4; dg++) {
            int row = dg * 16 + ln;
            #pragma unroll
            for (int ks = 0; ks < 2; ks++) {
                f16x8 vf = *(const f16x8*)&Vs[cur][row * 64 + (((qtr + ks*4) ^ (ln & 7)) * 8)];
                acc[dg] = __builtin_amdgcn_mfma_f32_16x16x32_f16(pfr[ks], vf, acc[dg], 0, 0, 0);
            }
        }
        __builtin_amdgcn_s_setprio(0);
        __syncthreads();
    }

    // ---- epilogue: single l reduction, divide, store f16
    float inv = 1.0f / redsum16(redsum32(l_part));
    float invm[4];
    #pragma unroll
    for (int m = 0; m < 4; m++) invm[m] = __shfl(inv, (l & 48) | (qtr * 4 + m), 64);
    size_t rowb = (size_t)b * NTOK + q0 + w * 16 + qtr * 4;
    #pragma unroll
    for (int dg = 0; dg < 4; dg++)
        #pragma unroll
        for (int m = 0; m < 4; m++)
            ao[(rowb + m) * DIM + h * HD + dg * 16 + ln] = (_Float16)(acc[dg][m] * invm[m]);
#undef STAGE
#undef LOADB
}

extern "C" void kernel_launch(void* const* d_in, const int* in_sizes, int n_in,
                              void* d_out, int out_size, void* d_ws, size_t ws_size,
                              hipStream_t stream) {
    const float* x     = (const float*)d_in[0];
    const float* ctx   = (const float*)d_in[1];
    const float* bias  = (const float*)d_in[2];
    const float* Wq    = (const float*)d_in[3];
    const float* Wk    = (const float*)d_in[4];
    const float* Wv    = (const float*)d_in[5];
    const float* Wo    = (const float*)d_in[6];
    const float* bo    = (const float*)d_in[7];
    const float* gamma = (const float*)d_in[8];
    const float* beta  = (const float*)d_in[9];
    float* out = (float*)d_out;

    _Float16* ws  = (_Float16*)d_ws;
    _Float16* xn  = ws;                                  // 8192*1024
    _Float16* cn  = xn  + (size_t)MROWS * DIM;           // 8192*1024
    _Float16* wqT = cn  + (size_t)MROWS * DIM;           // 1024*1024
    _Float16* wkT = wqT + (size_t)DIM * DIM;             // [wkT|wvT] contiguous = fused K/V weights
    _Float16* wvT = wkT + (size_t)DIM * DIM;
    _Float16* woT = wvT + (size_t)DIM * DIM;
    _Float16* qbf = woT + (size_t)DIM * DIM;             // [b][h][n][d]  (pre-scaled by SCL)
    _Float16* kbf = qbf + (size_t)MROWS * DIM;           // [b][h][n][d]
    _Float16* vtb = kbf + (size_t)MROWS * DIM;           // [b][h][d][n]
    _Float16* aob = vtb + (size_t)MROWS * DIM;           // [b][n][h*d]
    _Float16* bias2 = ws;   // reuses xn+cn (32 MB) AFTER the Q/K/V GEMMs consume them

    ln_kernel<<<dim3(2 * MROWS), dim3(256), 0, stream>>>(x, ctx, gamma, beta, xn, cn);
    wtrans_kernel<<<dim3(32, 32, 4), dim3(32, 8), 0, stream>>>(Wq, Wk, Wv, Wo, wqT, wkT, wvT, woT);
    gemm_bt<1><<<dim3(64, 8), dim3(256), 0, stream>>>(xn, wqT, qbf, nullptr, nullptr);
    gemm_bt<4><<<dim3(64, 16), dim3(256), 0, stream>>>(cn, wkT, kbf, vtb, nullptr);
    biasconv_kernel<<<dim3(8192), dim3(256), 0, stream>>>(bias, bias2);
    attn_kernel<<<dim3(NB * HEADS * 16), dim3(256), 0, stream>>>(qbf, kbf, vtb, bias2, aob);
    gemm_bt<3><<<dim3(64, 8), dim3(256), 0, stream>>>(aob, woT, out, nullptr, bo);
}

// Round 11
// 227.281 us; speedup vs baseline: 1.0258x; 1.0258x over previous
//
#include <hip/hip_runtime.h>
#include <hip/hip_bf16.h>
#include <stdint.h>

#define DIM   1024
#define HEADS 16
#define HD    64
#define NB    8
#define NTOK  1024
#define MROWS (NB*NTOK)   // 8192 rows for x and for context

#define LOG2E 1.4426950408889634f
#define SCL   (0.125f * LOG2E)

typedef __attribute__((ext_vector_type(8))) _Float16 f16x8;
typedef __attribute__((ext_vector_type(4))) _Float16 f16x4;
typedef __attribute__((ext_vector_type(4))) float    f32x4;

typedef unsigned int uint_as1 __attribute__((address_space(1)));
typedef unsigned int uint_as3 __attribute__((address_space(3)));

__device__ __forceinline__ void gload16(const void* g, void* l) {
    __builtin_amdgcn_global_load_lds((const uint_as1*)g, (uint_as3*)l, 16, 0, 0);
}

__device__ __forceinline__ unsigned pkrtz(float a, float b) {
    auto h = __builtin_amdgcn_cvt_pkrtz(a, b);   // __fp16 ext_vector(2)
    return __builtin_bit_cast(unsigned, h);
}

// ---- permlane pair swaps (gfx950), with verified shuffle fallback ----
#if __has_builtin(__builtin_amdgcn_permlane32_swap)
__device__ __forceinline__ void swap32(unsigned& a, unsigned& b) {
    auto r = __builtin_amdgcn_permlane32_swap(a, b, false, false);
    a = r[0]; b = r[1];
}
#else
__device__ __forceinline__ void swap32(unsigned& a, unsigned& b) {
    unsigned as = (unsigned)__shfl_xor((int)a, 32, 64);
    unsigned bs = (unsigned)__shfl_xor((int)b, 32, 64);
    bool lo = ((threadIdx.x & 63) < 32);
    unsigned na = lo ? a : bs, nb = lo ? as : b;
    a = na; b = nb;
}
#endif
#if __has_builtin(__builtin_amdgcn_permlane16_swap)
__device__ __forceinline__ void swap16(unsigned& a, unsigned& b) {
    auto r = __builtin_amdgcn_permlane16_swap(a, b, false, false);
    a = r[0]; b = r[1];
}
#else
__device__ __forceinline__ void swap16(unsigned& a, unsigned& b) {
    unsigned as = (unsigned)__shfl_xor((int)a, 16, 64);
    unsigned bs = (unsigned)__shfl_xor((int)b, 16, 64);
    bool ev = ((threadIdx.x & 16) == 0);
    unsigned na = ev ? a : bs, nb = ev ? as : b;
    a = na; b = nb;
}
#endif
__device__ __forceinline__ float redsum32(float x) {
    unsigned a = __builtin_bit_cast(unsigned, x), b = a;
    swap32(a, b);
    return __builtin_bit_cast(float, a) + __builtin_bit_cast(float, b);
}
__device__ __forceinline__ float redsum16(float x) {
    unsigned a = __builtin_bit_cast(unsigned, x), b = a;
    swap16(a, b);
    return __builtin_bit_cast(float, a) + __builtin_bit_cast(float, b);
}

// ---------------- Prep: LayerNorm (blocks 0..16383) + W transpose ----------
__global__ __launch_bounds__(256) void prep_kernel(const float* __restrict__ x,
                                                   const float* __restrict__ ctx,
                                                   const float* __restrict__ gamma,
                                                   const float* __restrict__ beta,
                                                   _Float16* __restrict__ xn,
                                                   _Float16* __restrict__ cn,
                                                   const float* __restrict__ Wq, const float* __restrict__ Wk,
                                                   const float* __restrict__ Wv, const float* __restrict__ Wo,
                                                   _Float16* __restrict__ Tq, _Float16* __restrict__ Tk,
                                                   _Float16* __restrict__ Tv, _Float16* __restrict__ To) {
    __shared__ float redm[8];
    __shared__ float tile[32][33];
    int bid = blockIdx.x;
    int t = threadIdx.x;
    if (bid < 2 * MROWS) {               // ---- LayerNorm path
        int row = bid;
        const float* src; _Float16* dst;
        if (row < MROWS) { src = x + (size_t)row * DIM;   dst = xn + (size_t)row * DIM; }
        else             { int r = row - MROWS;
                           src = ctx + (size_t)r * DIM;   dst = cn + (size_t)r * DIM; }
        float4 v = *(const float4*)(src + t * 4);
        float s  = v.x + v.y + v.z + v.w;
        float s2 = v.x*v.x + v.y*v.y + v.z*v.z + v.w*v.w;
        #pragma unroll
        for (int o = 32; o; o >>= 1) { s += __shfl_xor(s, o, 64); s2 += __shfl_xor(s2, o, 64); }
        int w = t >> 6, l = t & 63;
        if (l == 0) { redm[w] = s; redm[4 + w] = s2; }
        __syncthreads();
        s  = redm[0] + redm[1] + redm[2] + redm[3];
        s2 = redm[4] + redm[5] + redm[6] + redm[7];
        float mu   = s * (1.0f / DIM);
        float rstd = rsqrtf(s2 * (1.0f / DIM) - mu * mu + 1e-5f);
        float4 g  = *(const float4*)(gamma + t * 4);
        float4 bb = *(const float4*)(beta  + t * 4);
        f16x4 o;
        o[0] = (_Float16)((v.x - mu) * rstd * g.x + bb.x);
        o[1] = (_Float16)((v.y - mu) * rstd * g.y + bb.y);
        o[2] = (_Float16)((v.z - mu) * rstd * g.z + bb.z);
        o[3] = (_Float16)((v.w - mu) * rstd * g.w + bb.w);
        *(f16x4*)(dst + t * 4) = o;
    } else {                              // ---- weight transpose path
        int fid = bid - 2 * MROWS;        // 4096 blocks
        int m = fid >> 10;
        int rem = fid & 1023;
        int j0 = (rem & 31) * 32, k0 = (rem >> 5) * 32;
        const float* W = (m == 0) ? Wq : (m == 1) ? Wk : (m == 2) ? Wv : Wo;
        _Float16*    T = (m == 0) ? Tq : (m == 1) ? Tk : (m == 2) ? Tv : To;
        int tx = t & 31, ty = t >> 5;     // 32 x 8
        #pragma unroll
        for (int i = 0; i < 4; i++) tile[ty + i*8][tx] = W[(size_t)(k0 + ty + i*8) * DIM + j0 + tx];
        __syncthreads();
        #pragma unroll
        for (int i = 0; i < 4; i++) T[(size_t)(j0 + ty + i*8) * DIM + k0 + tx] = (_Float16)tile[tx][ty + i*8];
    }
}

// ---------------- Fused QKV GEMM: 1536 blocks, BK=64, XOR-swizzled LDS -----
// mode 0: Q = xn @ WqT^T * SCL -> [b][h][n][d]
// mode 1: K = cn @ WkT^T       -> [b][h][n][d]
// mode 2: V^T = (cn @ WvT^T)^T -> [b][h][d][n]
__global__ __launch_bounds__(256) void gemm_qkv(const _Float16* __restrict__ xn,
                                                const _Float16* __restrict__ cn,
                                                const _Float16* __restrict__ wqT,
                                                const _Float16* __restrict__ wkT,
                                                const _Float16* __restrict__ wvT,
                                                _Float16* __restrict__ qbf,
                                                _Float16* __restrict__ kbf,
                                                _Float16* __restrict__ vtb) {
    __shared__ _Float16 As[128 * 64];
    __shared__ _Float16 Bs[128 * 64];
    const int K = DIM;
    int mode = blockIdx.y >> 3;
    int n0 = (blockIdx.y & 7) * 128;
    int m0 = blockIdx.x * 128;
    const _Float16* A  = (mode == 0) ? xn : cn;
    const _Float16* BT = (mode == 0) ? wqT : (mode == 1) ? wkT : wvT;
    int t = threadIdx.x, w = t >> 6, l = t & 63;
    int wr = w >> 1, wc = w & 1, ln = l & 15, qtr = l >> 4;
    f32x4 acc[4][4] = {};
    int srow = w * 8 + (l >> 3);
    int cg   = (l & 7) ^ (srow & 7);
    const _Float16* Ag = A  + (size_t)(m0 + srow) * K + cg * 8;
    const _Float16* Bg = BT + (size_t)(n0 + srow) * K + cg * 8;
    for (int kt = 0; kt < K; kt += 64) {
        #pragma unroll
        for (int p = 0; p < 4; p++) {
            gload16(Ag + (size_t)(p * 32) * K, &As[(p * 32 + w * 8) * 64]);
            gload16(Bg + (size_t)(p * 32) * K, &Bs[(p * 32 + w * 8) * 64]);
        }
        Ag += 64; Bg += 64;
        __syncthreads();
        #pragma unroll
        for (int kk = 0; kk < 2; kk++) {
            f16x8 af[4], bfr[4];
            #pragma unroll
            for (int r = 0; r < 4; r++)
                af[r]  = *(const f16x8*)&As[(wr * 64 + r * 16 + ln) * 64 + (((qtr + kk*4) ^ (ln & 7)) * 8)];
            #pragma unroll
            for (int c = 0; c < 4; c++)
                bfr[c] = *(const f16x8*)&Bs[(wc * 64 + c * 16 + ln) * 64 + (((qtr + kk*4) ^ (ln & 7)) * 8)];
            #pragma unroll
            for (int r = 0; r < 4; r++)
                #pragma unroll
                for (int c = 0; c < 4; c++)
                    acc[r][c] = __builtin_amdgcn_mfma_f32_16x16x32_f16(af[r], bfr[c], acc[r][c], 0, 0, 0);
        }
        __syncthreads();
    }
    #pragma unroll
    for (int r = 0; r < 4; r++)
        #pragma unroll
        for (int c = 0; c < 4; c++) {
            int gn = n0 + wc * 64 + c * 16 + ln;
            int h = gn >> 6, d = gn & 63;
            #pragma unroll
            for (int q = 0; q < 4; q++) {
                int gm = m0 + wr * 64 + r * 16 + qtr * 4 + q;
                int b = gm >> 10, n = gm & 1023;
                float v = acc[r][c][q];
                if (mode == 0)
                    qbf[(((size_t)(b * HEADS + h) * NTOK + n) << 6) + d] = (_Float16)(v * SCL);
                else if (mode == 1)
                    kbf[(((size_t)(b * HEADS + h) * NTOK + n) << 6) + d] = (_Float16)v;
                else
                    vtb[(((size_t)(b * HEADS + h) * HD + d) << 10) + n] = (_Float16)v;
            }
        }
}

// ---------------- Output GEMM: out = aob @ WoT^T + bo (fp32) ---------------
__global__ __launch_bounds__(256) void gemm_out(const _Float16* __restrict__ A,
                                                const _Float16* __restrict__ BT,
                                                float* __restrict__ Cout,
                                                const float* __restrict__ bias) {
    __shared__ _Float16 As[128 * 64];
    __shared__ _Float16 Bs[128 * 64];
    const int K = DIM;
    int m0 = blockIdx.x * 128, n0 = blockIdx.y * 128;
    int t = threadIdx.x, w = t >> 6, l = t & 63;
    int wr = w >> 1, wc = w & 1, ln = l & 15, qtr = l >> 4;
    f32x4 acc[4][4] = {};
    int srow = w * 8 + (l >> 3);
    int cg   = (l & 7) ^ (srow & 7);
    const _Float16* Ag = A  + (size_t)(m0 + srow) * K + cg * 8;
    const _Float16* Bg = BT + (size_t)(n0 + srow) * K + cg * 8;
    for (int kt = 0; kt < K; kt += 64) {
        #pragma unroll
        for (int p = 0; p < 4; p++) {
            gload16(Ag + (size_t)(p * 32) * K, &As[(p * 32 + w * 8) * 64]);
            gload16(Bg + (size_t)(p * 32) * K, &Bs[(p * 32 + w * 8) * 64]);
        }
        Ag += 64; Bg += 64;
        __syncthreads();
        #pragma unroll
        for (int kk = 0; kk < 2; kk++) {
            f16x8 af[4], bfr[4];
            #pragma unroll
            for (int r = 0; r < 4; r++)
                af[r]  = *(const f16x8*)&As[(wr * 64 + r * 16 + ln) * 64 + (((qtr + kk*4) ^ (ln & 7)) * 8)];
            #pragma unroll
            for (int c = 0; c < 4; c++)
                bfr[c] = *(const f16x8*)&Bs[(wc * 64 + c * 16 + ln) * 64 + (((qtr + kk*4) ^ (ln & 7)) * 8)];
            #pragma unroll
            for (int r = 0; r < 4; r++)
                #pragma unroll
                for (int c = 0; c < 4; c++)
                    acc[r][c] = __builtin_amdgcn_mfma_f32_16x16x32_f16(af[r], bfr[c], acc[r][c], 0, 0, 0);
        }
        __syncthreads();
    }
    #pragma unroll
    for (int r = 0; r < 4; r++)
        #pragma unroll
        for (int c = 0; c < 4; c++) {
            int gn = n0 + wc * 64 + c * 16 + ln;
            float bv = bias[gn];
            #pragma unroll
            for (int q = 0; q < 4; q++) {
                int gm = m0 + wr * 64 + r * 16 + qtr * 4 + q;
                Cout[(size_t)gm * DIM + gn] = acc[r][c][q] + bv;
            }
        }
}

// ---------------- Fused flash attention -----------------------------------
// Block = (b, h, 64 q rows); 4 waves x 16 q rows each. 2048 blocks.
// XCD swizzle groups blocks by h-PAIR (bias slices L2/L3-resident per XCD).
// Swapped QK^T with f32-bias*log2e as MFMA C-init (Q pre-scaled by SCL).
// No online max (log2-domain scores bounded); l reduced once in epilogue.
// Permlane P^T->A-frag exchange.
__global__ __launch_bounds__(256) void attn_kernel(const _Float16* __restrict__ qb,
                                                   const _Float16* __restrict__ kb,
                                                   const _Float16* __restrict__ vt,
                                                   const float* __restrict__ bias,
                                                   _Float16* __restrict__ ao) {
    __shared__ _Float16 Kt[2][64 * 64];
    __shared__ _Float16 Vs[2][64 * 64];
    int bid = blockIdx.x;
    // XCD = bid&7 = h-pair; rem packs (h&1, b, qt)
    int rem = bid >> 3;
    int h = (bid & 7) * 2 + (rem & 1);
    int b = (rem >> 1) & 7;
    int qt = rem >> 4;            // 0..15
    int q0 = qt * 64;
    int t = threadIdx.x, w = t >> 6, l = t & 63, ln = l & 15, qtr = l >> 4;
    const _Float16* qbase = qb + (size_t)(b * HEADS + h) * NTOK * HD;
    const _Float16* kbase = kb + (size_t)(b * HEADS + h) * NTOK * HD;
    const _Float16* vbase = vt + (size_t)(b * HEADS + h) * HD * NTOK;
    const float*    bbase = bias + ((size_t)h * NTOK + q0 + w * 16) * NTOK;

    // Q fragments (B-operand): lane ln = q col, qtr*8 = k offset
    f16x8 qfr[2];
    #pragma unroll
    for (int ks = 0; ks < 2; ks++)
        qfr[ks] = *(const f16x8*)&qbase[(size_t)(q0 + w*16 + ln) * HD + ks*32 + qtr*8];

#define STAGE(BUF, J0) do {                                                     \
        int rb_ = w * 16;                                                       \
        _Float16* kl_ = &Kt[BUF][rb_ * 64];                                     \
        _Float16* vl_ = &Vs[BUF][rb_ * 64];                                     \
        int r_ = rb_ + (l >> 3); int cg_ = (l & 7) ^ (r_ & 7);                  \
        gload16(kbase + (size_t)((J0) + r_) * HD + cg_ * 8, kl_);               \
        gload16(vbase + (size_t)r_ * NTOK + (J0) + cg_ * 8, vl_);               \
        r_ += 8; cg_ = (l & 7) ^ (r_ & 7);                                      \
        gload16(kbase + (size_t)((J0) + r_) * HD + cg_ * 8, kl_ + 8 * 64);      \
        gload16(vbase + (size_t)r_ * NTOK + (J0) + cg_ * 8, vl_ + 8 * 64);      \
    } while (0)

#define LOADB(DST, TT) do {                                                     \
        _Pragma("unroll")                                                       \
        for (int r_ = 0; r_ < 4; r_++)                                          \
            DST[r_] = *(const float4*)&bbase[(size_t)ln * NTOK                  \
                                             + (TT)*64 + qtr*4 + r_*16];        \
    } while (0)

    STAGE(0, 0);
    float4 bpp[2][4];             // [ping][r], static-indexed after unroll
    LOADB(bpp[0], 0);
    __syncthreads();

    float l_part = 0.f;
    f32x4 acc[4] = {};

    #pragma unroll 2
    for (int tt = 0; tt < 16; tt++) {
        int cur = tt & 1;
        if (tt < 15) { STAGE(cur ^ 1, (tt + 1) * 64); LOADB(bpp[cur ^ 1], tt + 1); }

        // ---- QK^T (swapped) with bias C-init (f32 bias * log2e):
        // st2[r][m] = LOG2E*bias + S_log2 at [j=tt*64+r*16+qtr*4+m][q=q0+w*16+ln]
        f32x4 st2[4];
        #pragma unroll
        for (int r = 0; r < 4; r++) {
            float4 bb = bpp[cur][r];
            f32x4 ci = {bb.x * LOG2E, bb.y * LOG2E, bb.z * LOG2E, bb.w * LOG2E};
            st2[r] = ci;
        }
        __builtin_amdgcn_s_setprio(1);
        #pragma unroll
        for (int r = 0; r < 4; r++) {
            int row = r * 16 + ln;
            #pragma unroll
            for (int ks = 0; ks < 2; ks++) {
                f16x8 kf = *(const f16x8*)&Kt[cur][row * 64 + (((qtr + ks*4) ^ (ln & 7)) * 8)];
                st2[r] = __builtin_amdgcn_mfma_f32_16x16x32_f16(kf, qfr[ks], st2[r], 0, 0, 0);
            }
        }
        __builtin_amdgcn_s_setprio(0);

        // ---- softmax numerator (no max: P = exp2(s) directly, f16-safe)
        float sig = 0.f;
        unsigned pk2[4][2];
        #pragma unroll
        for (int r = 0; r < 4; r++) {
            float p0 = exp2f(st2[r][0]);
            float p1 = exp2f(st2[r][1]);
            float p2 = exp2f(st2[r][2]);
            float p3 = exp2f(st2[r][3]);
            sig += (p0 + p1) + (p2 + p3);
            pk2[r][0] = pkrtz(p0, p1);
            pk2[r][1] = pkrtz(p2, p3);
        }
        l_part += sig;

        // in-register P^T -> A-frag exchange via permlane swaps
        f16x8 pfr[2];
        #pragma unroll
        for (int ks = 0; ks < 2; ks++) {
            unsigned pw[4];
            #pragma unroll
            for (int c = 0; c < 2; c++) {
                unsigned U = pk2[2*ks][c], T = pk2[2*ks + 1][c];
                swap32(U, T);
                swap16(U, T);
                pw[c]     = U;    // elems e=0..3
                pw[2 + c] = T;    // elems e=4..7
            }
            pfr[ks] = __builtin_bit_cast(f16x8, *(const uint4*)pw);
        }

        // ---- PV: acc[dg] += P @ V
        __builtin_amdgcn_s_setprio(1);
        #pragma unroll
        for (int dg = 0; dg < 4; dg++) {
            int row = dg * 16 + ln;
            #pragma unroll
            for (int ks = 0; ks < 2; ks++) {
                f16x8 vf = *(const f16x8*)&Vs[cur][row * 64 + (((qtr + ks*4) ^ (ln & 7)) * 8)];
                acc[dg] = __builtin_amdgcn_mfma_f32_16x16x32_f16(pfr[ks], vf, acc[dg], 0, 0, 0);
            }
        }
        __builtin_amdgcn_s_setprio(0);
        __syncthreads();
    }

    // ---- epilogue: single l reduction, divide, store f16
    float inv = 1.0f / redsum16(redsum32(l_part));
    float invm[4];
    #pragma unroll
    for (int m = 0; m < 4; m++) invm[m] = __shfl(inv, (l & 48) | (qtr * 4 + m), 64);
    size_t rowb = (size_t)b * NTOK + q0 + w * 16 + qtr * 4;
    #pragma unroll
    for (int dg = 0; dg < 4; dg++)
        #pragma unroll
        for (int m = 0; m < 4; m++)
            ao[(rowb + m) * DIM + h * HD + dg * 16 + ln] = (_Float16)(acc[dg][m] * invm[m]);
#undef STAGE
#undef LOADB
}

extern "C" void kernel_launch(void* const* d_in, const int* in_sizes, int n_in,
                              void* d_out, int out_size, void* d_ws, size_t ws_size,
                              hipStream_t stream) {
    const float* x     = (const float*)d_in[0];
    const float* ctx   = (const float*)d_in[1];
    const float* bias  = (const float*)d_in[2];
    const float* Wq    = (const float*)d_in[3];
    const float* Wk    = (const float*)d_in[4];
    const float* Wv    = (const float*)d_in[5];
    const float* Wo    = (const float*)d_in[6];
    const float* bo    = (const float*)d_in[7];
    const float* gamma = (const float*)d_in[8];
    const float* beta  = (const float*)d_in[9];
    float* out = (float*)d_out;

    _Float16* ws  = (_Float16*)d_ws;
    _Float16* xn  = ws;                                  // 8192*1024
    _Float16* cn  = xn  + (size_t)MROWS * DIM;           // 8192*1024
    _Float16* wqT = cn  + (size_t)MROWS * DIM;           // 1024*1024
    _Float16* wkT = wqT + (size_t)DIM * DIM;
    _Float16* wvT = wkT + (size_t)DIM * DIM;
    _Float16* woT = wvT + (size_t)DIM * DIM;
    _Float16* qbf = woT + (size_t)DIM * DIM;             // [b][h][n][d]  (pre-scaled by SCL)
    _Float16* kbf = qbf + (size_t)MROWS * DIM;           // [b][h][n][d]
    _Float16* vtb = kbf + (size_t)MROWS * DIM;           // [b][h][d][n]
    _Float16* aob = vtb + (size_t)MROWS * DIM;           // [b][n][h*d]

    prep_kernel<<<dim3(2 * MROWS + 4096), dim3(256), 0, stream>>>(
        x, ctx, gamma, beta, xn, cn, Wq, Wk, Wv, Wo, wqT, wkT, wvT, woT);
    gemm_qkv<<<dim3(64, 24), dim3(256), 0, stream>>>(xn, cn, wqT, wkT, wvT, qbf, kbf, vtb);
    attn_kernel<<<dim3(NB * HEADS * 16), dim3(256), 0, stream>>>(qbf, kbf, vtb, bias, aob);
    gemm_out<<<dim3(64, 8), dim3(256), 0, stream>>>(aob, woT, out, bo);
}